// Round 12
// baseline (636.401 us; speedup 1.0000x reference)
//
#include <hip/hip_runtime.h>
#include <cstdint>

// RGPR-GNN (GPR-GNN + RGCN basis-decomp convs) for MI355X.
// R12: LLC-resident aggB via CHUNKING. R11 counters: agg writes 87.5 MB/layer
// straight to HBM and gemm re-fetches ~45 MB of it -> ~400 MB of the ~760 MB
// total traffic is the aggB round-trip. Now each layer runs in 2 chunks of
// 25000 dsts, agg->gemm back-to-back, REUSING one 43.8 MB aggC buffer: the
// re-touched address range stays hot in the 256 MB Infinity Cache, so the HBM
// write-through + re-fetch mostly vanish. agg also drops the shfl broadcast:
// esrc[p]/drs[] at wave-uniform p compile to scalar loads (constant cache).
// Structure otherwise = R11: no fp32 hidden (b0..b3 bf16, final combines),
// cast_x folded into lin1, gemm_layer M=32 + B LDS-staged, (dst,rel) sort once.

constexpr int N_NODES  = 50000;
constexpr int E_EDGES  = 600000;
constexpr int R_REL    = 7;
constexpr int HID      = 128;
constexpr int IN_C     = 256;
constexpr int L_LAYERS = 3;
constexpr int AGG_COLS = 896;           // 7*128 aggregated message columns
constexpr int K_CAT    = 1024;          // 128 self + 896 agg
constexpr int NR       = N_NODES * R_REL;            // 350000 segments
constexpr int SCANR_BLOCKS = (NR + 255) / 256;       // 1368
constexpr int CHUNK    = 25000;         // dsts per agg->gemm chunk (2 chunks)

#define DEVI __device__ __forceinline__

using short8  = __attribute__((ext_vector_type(8))) short;
using floatx4 = __attribute__((ext_vector_type(4))) float;

DEVI unsigned short f2bf(float f) {
  unsigned u = __float_as_uint(f);
  unsigned r = (u + 0x7FFFu + ((u >> 16) & 1u)) >> 16;  // RNE
  return (unsigned short)r;
}
DEVI float bf2f(unsigned short h) { return __uint_as_float(((unsigned)h) << 16); }

// ---------------------------------------------------------------- prep casts
__global__ __launch_bounds__(256) void cast_w1_kernel(
    const float* __restrict__ w1, unsigned short* __restrict__ w1T)
{
  int t = blockIdx.x * 256 + threadIdx.x;      // 128*256
  if (t >= HID * IN_C) return;
  int m = t >> 8, k = t & 255;
  w1T[m * IN_C + k] = f2bf(w1[k * HID + m]);
}

// Wcat2T bf16: [L][f=128][k=1024]. k<128 -> roots[l][k][f]; k>=128 -> W[r][d][f]
__global__ __launch_bounds__(256) void build_wcat2(
    const float* __restrict__ comps,   // [L,R,8]
    const float* __restrict__ bases,   // [L,8,128,128]
    const float* __restrict__ roots,   // [L,128,128]
    unsigned short* __restrict__ wcat2T)
{
  int t = blockIdx.x * 256 + threadIdx.x;
  if (t >= L_LAYERS * 128 * K_CAT) return;
  int l   = t >> 17;
  int rem = t & 131071;
  int f   = rem >> 10;
  int k   = rem & 1023;
  float v;
  if (k < 128) {
    v = roots[((size_t)l * 128 + k) * 128 + f];
  } else {
    int r = (k - 128) >> 7, d = (k - 128) & 127;
    const float* cp = comps + ((size_t)l * R_REL + r) * 8;
    const float* bp = bases + (((size_t)l * 8) * 128 + d) * 128 + f;
    float s = 0.f;
#pragma unroll
    for (int b = 0; b < 8; ++b) s += cp[b] * bp[(size_t)b * 128 * 128];
    v = s;
  }
  wcat2T[t] = f2bf(v);
}

// ---------------------------------------------------------------- histogram (dst,rel)
__global__ __launch_bounds__(256) void hist_kernel(
    const int* __restrict__ ei, const int* __restrict__ et,
    int* __restrict__ cntRel)
{
  int e = blockIdx.x * 256 + threadIdx.x;
  if (e >= E_EDGES) return;
  atomicAdd(&cntRel[ei[E_EDGES + e] * R_REL + et[e]], 1);
}

// ---------------------------------------------------------------- scan over NR
__global__ __launch_bounds__(256) void scanA_kernel(
    const int* __restrict__ cnt, int* __restrict__ tmpOff,
    int* __restrict__ blockSums)
{
  __shared__ int s[256];
  int i = blockIdx.x * 256 + threadIdx.x;
  int v = (i < NR) ? cnt[i] : 0;
  s[threadIdx.x] = v;
  __syncthreads();
#pragma unroll
  for (int d = 1; d < 256; d <<= 1) {
    int t = (threadIdx.x >= d) ? s[threadIdx.x - d] : 0;
    __syncthreads();
    s[threadIdx.x] += t;
    __syncthreads();
  }
  if (i < NR) tmpOff[i] = s[threadIdx.x] - v;   // exclusive within block
  if (threadIdx.x == 255) blockSums[blockIdx.x] = s[255];
}

// single block, serial chunks with carry (SCANR_BLOCKS = 1368)
__global__ __launch_bounds__(256) void scanB_kernel(int* __restrict__ bs)
{
  __shared__ int s[256];
  __shared__ int carry;
  if (threadIdx.x == 0) carry = 0;
  __syncthreads();
  for (int base = 0; base < SCANR_BLOCKS; base += 256) {
    int cOld = carry;
    int i = base + threadIdx.x;
    int v = (i < SCANR_BLOCKS) ? bs[i] : 0;
    s[threadIdx.x] = v;
    __syncthreads();
#pragma unroll
    for (int d = 1; d < 256; d <<= 1) {
      int t = (threadIdx.x >= d) ? s[threadIdx.x - d] : 0;
      __syncthreads();
      s[threadIdx.x] += t;
      __syncthreads();
    }
    if (i < SCANR_BLOCKS) bs[i] = s[threadIdx.x] - v + cOld;  // exclusive
    __syncthreads();
    if (threadIdx.x == 0) carry = cOld + s[255];
    __syncthreads();
  }
}

__global__ __launch_bounds__(256) void scanC_kernel(
    const int* __restrict__ tmpOff, const int* __restrict__ blockSums,
    int* __restrict__ drs)
{
  int i = blockIdx.x * 256 + threadIdx.x;
  if (i < NR) drs[i] = tmpOff[i] + blockSums[blockIdx.x];
  if (i == 0) drs[NR] = E_EDGES;
}

// ---------------------------------------------------------------- placement
__global__ __launch_bounds__(256) void place_kernel(
    const int* __restrict__ ei, const int* __restrict__ et,
    const int* __restrict__ drs, int* __restrict__ cursor,
    unsigned short* __restrict__ esrc)
{
  int e = blockIdx.x * 256 + threadIdx.x;
  if (e >= E_EDGES) return;
  int seg = ei[E_EDGES + e] * R_REL + et[e];
  int pos = drs[seg] + atomicAdd(&cursor[seg], 1);
  esrc[pos] = (unsigned short)ei[e];   // src < 50000 < 65536
}

// ---------------------------------------------------------------- aggregation (chunk)
// One wave per dst; 64 lanes x 2 dims = full 256B curA row per edge (coalesced).
// Edges sorted (dst,rel): per-relation float2 REGISTER accum; mean = 1/(b-a).
// esrc[p]/drs[] at wave-uniform p -> scalar loads (constant cache). Output goes
// to the chunk-local aggC buffer (LLC-resident, reused across chunks/layers).
__global__ __launch_bounds__(256) void agg_chunk_kernel(
    const unsigned short* __restrict__ curA,   // [N,128] bf16
    const unsigned short* __restrict__ esrc,   // sorted by (dst,rel)
    const int* __restrict__ drs,               // [N*R+1] segment starts
    unsigned short* __restrict__ aggC,         // [CHUNK,896] bf16
    int dstBase, int dstEnd)
{
  const int lane = threadIdx.x & 63;
  const int dst  = dstBase + blockIdx.x * 4 + (threadIdx.x >> 6);
  if (dst >= dstEnd) return;
  const unsigned* curW = (const unsigned*)curA;   // 64 uints per node row
  const int segBase = dst * R_REL;
  const size_t outBase = (size_t)(dst - dstBase) * AGG_COLS;

  int aPrev = drs[segBase];
#pragma unroll
  for (int r = 0; r < R_REL; ++r) {
    int br = drs[segBase + r + 1];
    float sx = 0.f, sy = 0.f;
    for (int p = aPrev; p < br; ++p) {
      int src = (int)esrc[p];                     // wave-uniform -> scalar load
      unsigned v = curW[(size_t)src * 64 + lane];
      sx += bf2f((unsigned short)(v & 0xFFFF));
      sy += bf2f((unsigned short)(v >> 16));
    }
    int c = br - aPrev;
    float sc = (c > 0) ? 1.0f / (float)c : 0.f;
    unsigned pck = (unsigned)f2bf(sx * sc) | ((unsigned)f2bf(sy * sc) << 16);
    *(unsigned*)(aggC + outBase + r * HID + lane * 2) = pck;
    aPrev = br;
  }
}

// ---------------------------------------------------------------- lin1 MFMA GEMM
// M=64 tile (grid 782), K=256 in 2 phases; x read fp32 + cast DURING staging.
// Output: b0 = bf16(t0*(x@w1+b1)) ONLY (no fp32 hidden).
__global__ __launch_bounds__(256) void gemm_lin1(
    const float* __restrict__ x,              // [N,256] fp32
    const unsigned short* __restrict__ BT,    // w1T [128,256] bf16
    const float* __restrict__ bias,
    const float* __restrict__ temp,
    unsigned short* __restrict__ b0out)       // [N,128] bf16
{
  __shared__ unsigned short Atile[64][136];    // 17.4 KB
  __shared__ unsigned short Btile[128][136];   // 34.8 KB
  const int tid  = threadIdx.x;
  const int row0 = blockIdx.x * 64;
  const int lane = tid & 63;
  const int wid  = tid >> 6;
  const int wrow = (wid & 1) * 32;
  const int wcol = (wid >> 1) * 64;
  const int l15  = lane & 15;
  const int quad = lane >> 4;

  floatx4 acc[2][4] = {};

  for (int k0 = 0; k0 < IN_C; k0 += 128) {
#pragma unroll
    for (int it = 0; it < 4; ++it) {
      int chunk = it * 256 + tid;
      int r = chunk >> 4, cc = (chunk & 15) << 3;
      int grow = row0 + r;
      uint4 va = make_uint4(0u, 0u, 0u, 0u);
      if (grow < N_NODES) {
        const float* xp = x + (size_t)grow * IN_C + k0 + cc;
        float4 f0 = *(const float4*)xp;
        float4 f1 = *(const float4*)(xp + 4);
        va.x = (unsigned)f2bf(f0.x) | ((unsigned)f2bf(f0.y) << 16);
        va.y = (unsigned)f2bf(f0.z) | ((unsigned)f2bf(f0.w) << 16);
        va.z = (unsigned)f2bf(f1.x) | ((unsigned)f2bf(f1.y) << 16);
        va.w = (unsigned)f2bf(f1.z) | ((unsigned)f2bf(f1.w) << 16);
      }
      *(uint4*)(&Atile[r][cc]) = va;
    }
#pragma unroll
    for (int it = 0; it < 8; ++it) {
      int chunk = it * 256 + tid;
      int n = chunk >> 4, cc = (chunk & 15) << 3;
      *(uint4*)(&Btile[n][cc]) =
          *(const uint4*)(BT + (size_t)n * IN_C + k0 + cc);
    }
    __syncthreads();
#pragma unroll
    for (int ks = 0; ks < 4; ++ks) {
      int kc = ks * 32 + quad * 8;
      short8 af[2], bfr[4];
#pragma unroll
      for (int i = 0; i < 2; ++i)
        af[i] = *(const short8*)(&Atile[wrow + i * 16 + l15][kc]);
#pragma unroll
      for (int j = 0; j < 4; ++j)
        bfr[j] = *(const short8*)(&Btile[wcol + j * 16 + l15][kc]);
#pragma unroll
      for (int i = 0; i < 2; ++i)
#pragma unroll
        for (int j = 0; j < 4; ++j)
          acc[i][j] = __builtin_amdgcn_mfma_f32_16x16x32_bf16(
              af[i], bfr[j], acc[i][j], 0, 0, 0);
    }
    __syncthreads();
  }

  float t0 = temp[0];
#pragma unroll
  for (int i = 0; i < 2; ++i) {
    int lrow0 = wrow + i * 16 + quad * 4;
#pragma unroll
    for (int j = 0; j < 4; ++j) {
      int gcol = wcol + j * 16 + l15;
      float bb = bias[gcol];
#pragma unroll
      for (int r = 0; r < 4; ++r)
        Atile[lrow0 + r][gcol] = f2bf(t0 * (acc[i][j][r] + bb));
    }
  }
  __syncthreads();
#pragma unroll
  for (int it = 0; it < 4; ++it) {
    int chunk = it * 256 + tid;
    int r = chunk >> 4, cc = (chunk & 15) << 3;
    int grow = row0 + r;
    if (grow < N_NODES)
      *(uint4*)(b0out + (size_t)grow * HID + cc) = *(const uint4*)(&Atile[r][cc]);
  }
}

// ---------------------------------------------------------------- layer MFMA GEMM (chunk)
// M=32 tile, 4 waves of 16x64 (acc 1x4). A 8.7 KB + B 34.8 KB LDS = 43.5 KB.
// A rel-phases read the chunk-local aggC (LLC-hot). Epilogue: bf16 c only.
__global__ __launch_bounds__(256) void gemm_layer(
    const unsigned short* __restrict__ curA,   // [N,128] bf16 (in, = b_l)
    const unsigned short* __restrict__ aggC,   // [CHUNK,896] bf16
    const unsigned short* __restrict__ BT,     // wcat2T [128][1024] bf16
    const float* __restrict__ bias,
    unsigned short* __restrict__ bout,         // [N,128] bf16 (out, = b_{l+1})
    int layer, int dstBase, int dstEnd)
{
  __shared__ unsigned short Atile[32][136];    // 8.7 KB
  __shared__ unsigned short Btile[128][136];   // 34.8 KB
  const int tid  = threadIdx.x;
  const int row0 = dstBase + blockIdx.x * 32;
  const int lane = tid & 63;
  const int wid  = tid >> 6;
  const int wrow = (wid & 1) * 16;
  const int wcol = (wid >> 1) * 64;
  const int l15  = lane & 15;
  const int quad = lane >> 4;

  floatx4 acc[4] = {};

  for (int p = 0; p < 8; ++p) {
#pragma unroll
    for (int it = 0; it < 8; ++it) {
      int chunk = it * 256 + tid;
      int n = chunk >> 4, cc = (chunk & 15) << 3;
      *(uint4*)(&Btile[n][cc]) =
          *(const uint4*)(BT + (size_t)n * K_CAT + p * 128 + cc);
    }
#pragma unroll
    for (int it = 0; it < 2; ++it) {
      int chunk = it * 256 + tid;
      int r = chunk >> 4, cc = (chunk & 15) << 3;
      int grow = row0 + r;
      uint4 va = make_uint4(0u, 0u, 0u, 0u);
      if (grow < dstEnd) {
        if (p == 0)
          va = *(const uint4*)(curA + (size_t)grow * HID + cc);
        else
          va = *(const uint4*)(aggC + (size_t)(grow - dstBase) * AGG_COLS +
                               (p - 1) * 128 + cc);
      }
      *(uint4*)(&Atile[r][cc]) = va;
    }
    __syncthreads();
#pragma unroll
    for (int ks = 0; ks < 4; ++ks) {
      int kc = ks * 32 + quad * 8;
      short8 af = *(const short8*)(&Atile[wrow + l15][kc]);
      short8 bfr[4];
#pragma unroll
      for (int j = 0; j < 4; ++j)
        bfr[j] = *(const short8*)(&Btile[wcol + j * 16 + l15][kc]);
#pragma unroll
      for (int j = 0; j < 4; ++j)
        acc[j] = __builtin_amdgcn_mfma_f32_16x16x32_bf16(af, bfr[j], acc[j],
                                                         0, 0, 0);
    }
    __syncthreads();
  }

  const bool isLast = (layer == L_LAYERS - 1);
  {
    int lrow0 = wrow + quad * 4;
#pragma unroll
    for (int j = 0; j < 4; ++j) {
      int gcol = wcol + j * 16 + l15;
      float bb = bias[gcol];
#pragma unroll
      for (int r = 0; r < 4; ++r) {
        float c = acc[j][r] + bb;
        if (!isLast) c = fmaxf(c, 0.f);
        Atile[lrow0 + r][gcol] = f2bf(c);
      }
    }
  }
  __syncthreads();
#pragma unroll
  for (int it = 0; it < 2; ++it) {
    int chunk = it * 256 + tid;
    int r = chunk >> 4, cc = (chunk & 15) << 3;
    int grow = row0 + r;
    if (grow < dstEnd)
      *(uint4*)(bout + (size_t)grow * HID + cc) = *(const uint4*)(&Atile[r][cc]);
  }
}

// ---------------------------------------------------------------- final linear
// h[d] = b0 + temp[1]*b1 + temp[2]*b2 + temp[3]*b3 (bf16 terms), then lin2.
__global__ __launch_bounds__(256) void final_kernel(
    const unsigned short* __restrict__ b0, const unsigned short* __restrict__ b1,
    const unsigned short* __restrict__ b2v, const unsigned short* __restrict__ b3,
    const float* __restrict__ temp,
    const float* __restrict__ w2, const float* __restrict__ b2bias,
    float* __restrict__ out)
{
  int node = blockIdx.x * 4 + (threadIdx.x >> 6);
  int lane = threadIdx.x & 63;
  if (node >= N_NODES) return;
  float t1 = temp[1], t2 = temp[2], t3 = temp[3];
  size_t base = (size_t)node * 64 + lane;      // uint index: dims 2*lane,2*lane+1
  unsigned u0 = ((const unsigned*)b0)[base];
  unsigned u1 = ((const unsigned*)b1)[base];
  unsigned u2 = ((const unsigned*)b2v)[base];
  unsigned u3 = ((const unsigned*)b3)[base];
  float hx = bf2f((unsigned short)(u0 & 0xFFFF)) +
             t1 * bf2f((unsigned short)(u1 & 0xFFFF)) +
             t2 * bf2f((unsigned short)(u2 & 0xFFFF)) +
             t3 * bf2f((unsigned short)(u3 & 0xFFFF));
  float hy = bf2f((unsigned short)(u0 >> 16)) +
             t1 * bf2f((unsigned short)(u1 >> 16)) +
             t2 * bf2f((unsigned short)(u2 >> 16)) +
             t3 * bf2f((unsigned short)(u3 >> 16));
  int d0 = lane * 2, d1 = lane * 2 + 1;
  float a0 = hx * w2[d0 * 2 + 0] + hy * w2[d1 * 2 + 0];
  float a1 = hx * w2[d0 * 2 + 1] + hy * w2[d1 * 2 + 1];
#pragma unroll
  for (int off = 32; off > 0; off >>= 1) {
    a0 += __shfl_down(a0, off);
    a1 += __shfl_down(a1, off);
  }
  if (lane == 0) {
    out[node * 2 + 0] = a0 + b2bias[0];
    out[node * 2 + 1] = a1 + b2bias[1];
  }
}

// ---------------------------------------------------------------- launcher
extern "C" void kernel_launch(void* const* d_in, const int* in_sizes, int n_in,
                              void* d_out, int out_size, void* d_ws, size_t ws_size,
                              hipStream_t stream) {
  const float* x     = (const float*)d_in[0];
  const int*   ei    = (const int*)d_in[1];
  const int*   et    = (const int*)d_in[2];
  const float* temp  = (const float*)d_in[3];
  const float* w1    = (const float*)d_in[4];
  const float* b1    = (const float*)d_in[5];
  const float* w2    = (const float*)d_in[6];
  const float* b2    = (const float*)d_in[7];
  const float* comps = (const float*)d_in[8];
  const float* bases = (const float*)d_in[9];
  const float* roots = (const float*)d_in[10];
  const float* cbias = (const float*)d_in[11];

  char* ws = (char*)d_ws;
  size_t off = 0;
  auto take = [&](size_t bytes) {
    char* p = ws + off;
    off = (off + bytes + 255) & ~(size_t)255;
    return p;
  };
  unsigned short* wcat2T = (unsigned short*)take((size_t)L_LAYERS * 128 * K_CAT * 2); // 0.8 MB
  unsigned short* w1T    = (unsigned short*)take((size_t)HID * IN_C * 2);             // 64 KB
  int*   cntRel  = (int*)take((size_t)NR * 4);                  // 1.4 MB
  int*   tmpOffR = (int*)take((size_t)NR * 4);                  // 1.4 MB
  int*   blockSumsR = (int*)take((size_t)SCANR_BLOCKS * 4);
  int*   drs     = (int*)take((size_t)(NR + 1) * 4);            // 1.4 MB
  int*   cursorR = (int*)take((size_t)NR * 4);                  // 1.4 MB
  unsigned short* esrc = (unsigned short*)take((size_t)E_EDGES * 2); // 1.2 MB
  unsigned short* bl[L_LAYERS + 1];
  for (int i = 0; i <= L_LAYERS; ++i)
    bl[i] = (unsigned short*)take((size_t)N_NODES * HID * 2);   // 4 x 12.8 MB
  unsigned short* aggC = (unsigned short*)take((size_t)CHUNK * AGG_COLS * 2); // 43.8 MB

  hipMemsetAsync(cntRel, 0, (size_t)NR * 4, stream);
  hipMemsetAsync(cursorR, 0, (size_t)NR * 4, stream);

  hipLaunchKernelGGL(build_wcat2, dim3((L_LAYERS * 128 * K_CAT + 255) / 256),
                     dim3(256), 0, stream, comps, bases, roots, wcat2T);
  hipLaunchKernelGGL(cast_w1_kernel, dim3((HID * IN_C + 255) / 256), dim3(256),
                     0, stream, w1, w1T);
  hipLaunchKernelGGL(hist_kernel, dim3((E_EDGES + 255) / 256), dim3(256), 0,
                     stream, ei, et, cntRel);
  hipLaunchKernelGGL(scanA_kernel, dim3(SCANR_BLOCKS), dim3(256), 0, stream,
                     cntRel, tmpOffR, blockSumsR);
  hipLaunchKernelGGL(scanB_kernel, dim3(1), dim3(256), 0, stream, blockSumsR);
  hipLaunchKernelGGL(scanC_kernel, dim3(SCANR_BLOCKS), dim3(256), 0, stream,
                     tmpOffR, blockSumsR, drs);
  hipLaunchKernelGGL(place_kernel, dim3((E_EDGES + 255) / 256), dim3(256), 0,
                     stream, ei, et, drs, cursorR, esrc);

  const int rowBlocks64 = (N_NODES + 63) / 64;     // 782
  hipLaunchKernelGGL(gemm_lin1, dim3(rowBlocks64), dim3(256), 0, stream,
                     x, w1T, b1, temp, bl[0]);

  for (int l = 0; l < L_LAYERS; ++l) {
    for (int c0 = 0; c0 < N_NODES; c0 += CHUNK) {
      int cEnd = (c0 + CHUNK < N_NODES) ? (c0 + CHUNK) : N_NODES;
      int nc = cEnd - c0;
      hipLaunchKernelGGL(agg_chunk_kernel, dim3((nc + 3) / 4), dim3(256),
                         0, stream, bl[l], esrc, drs, aggC, c0, cEnd);
      hipLaunchKernelGGL(gemm_layer, dim3((nc + 31) / 32), dim3(256), 0, stream,
                         bl[l], aggC, wcat2T + (size_t)l * 128 * K_CAT,
                         cbias + (size_t)l * HID, bl[l + 1], l, c0, cEnd);
    }
  }

  hipLaunchKernelGGL(final_kernel, dim3((N_NODES + 3) / 4), dim3(256), 0, stream,
                     bl[0], bl[1], bl[2], bl[3], temp, w2, b2, (float*)d_out);
}

// Round 13
// 547.652 us; speedup vs baseline: 1.1621x; 1.1621x over previous
//
#include <hip/hip_runtime.h>
#include <cstdint>

// RGPR-GNN (GPR-GNN + RGCN basis-decomp convs) for MI355X.
// R13: agg->GEMM fused THROUGH LDS. R12 falsified the LLC-absorption idea
// (chunked aggC still wrote 43.75 MB/dispatch to HBM) and re-proved the shfl
// prefetch (scalar esrc loads dropped agg VALUBusy 53->26%). So: the per-layer
// aggregate now never leaves the CU. Block = 16 dsts:
//   phase 1: 4 waves run R11's exact agg loop (pk prefetch + shfl broadcast,
//            4 dsts/wave, fp32 reg accum) -> LDS tile [16][1032] bf16
//            (cols: 0..127 self, 128+r*128+d = rel-r mean).  ONE barrier.
//   phase 2: pure GEMM K=1024: A fragments from LDS; B fragments DIRECT from
//            global in FRAGMENT-MAJOR layout (wcat3) -> every B load is a
//            coalesced 16 B/lane dwordx4, L2-hot (fixes R8's strided-B trap);
//            no B LDS, no intra-loop barriers (R9's failure mode).
//   epilogue: c=(l<2?relu:id)(acc+bias); bout=bf16(c) via LDS transpose.
// aggB[N,896] buffer DELETED (-87.5 MB write -45 MB re-fetch per layer).
// Structure otherwise = R11: no fp32 hidden (b0..b3 bf16, final combines),
// cast_x folded into lin1, (dst,rel) sort once.

constexpr int N_NODES  = 50000;
constexpr int E_EDGES  = 600000;
constexpr int R_REL    = 7;
constexpr int HID      = 128;
constexpr int IN_C     = 256;
constexpr int L_LAYERS = 3;
constexpr int K_CAT    = 1024;          // 128 self + 896 agg
constexpr int NR       = N_NODES * R_REL;            // 350000 segments
constexpr int SCANR_BLOCKS = (NR + 255) / 256;       // 1368
constexpr int AROW     = 1032;          // LDS A row stride (shorts): 516 dw %32=4 -> 2-way max

#define DEVI __device__ __forceinline__

using short8  = __attribute__((ext_vector_type(8))) short;
using floatx4 = __attribute__((ext_vector_type(4))) float;

DEVI unsigned short f2bf(float f) {
  unsigned u = __float_as_uint(f);
  unsigned r = (u + 0x7FFFu + ((u >> 16) & 1u)) >> 16;  // RNE
  return (unsigned short)r;
}
DEVI float bf2f(unsigned short h) { return __uint_as_float(((unsigned)h) << 16); }

// ---------------------------------------------------------------- prep casts
__global__ __launch_bounds__(256) void cast_w1_kernel(
    const float* __restrict__ w1, unsigned short* __restrict__ w1T)
{
  int t = blockIdx.x * 256 + threadIdx.x;      // 128*256
  if (t >= HID * IN_C) return;
  int m = t >> 8, k = t & 255;
  w1T[m * IN_C + k] = f2bf(w1[k * HID + m]);
}

// wcat3: FRAGMENT-MAJOR weights for the fused GEMM.
// Linear idx (per layer) = ((((p*4+ks)*8 + j)*64 + lane)*8 + e), holding
// B[n][k] with n = j*16 + (lane&15), k = p*128 + ks*32 + (lane>>4)*8 + e.
// B[n][k]: k<128 -> roots[l][k][n]; k>=128 -> W[r=(k-128)>>7][d=(k-128)&127][n].
__global__ __launch_bounds__(256) void build_wcat3(
    const float* __restrict__ comps,   // [L,R,8]
    const float* __restrict__ bases,   // [L,8,128,128]
    const float* __restrict__ roots,   // [L,128,128]
    unsigned short* __restrict__ wcat3)
{
  int t = blockIdx.x * 256 + threadIdx.x;
  if (t >= L_LAYERS * 128 * K_CAT) return;
  int l    = t >> 17;
  int rem  = t & 131071;
  int e    = rem & 7;
  int lane = (rem >> 3) & 63;
  int j    = (rem >> 9) & 7;
  int ks   = (rem >> 12) & 3;
  int p    = (rem >> 14) & 7;
  int n = j * 16 + (lane & 15);
  int k = p * 128 + ks * 32 + (lane >> 4) * 8 + e;
  float v;
  if (k < 128) {
    v = roots[((size_t)l * 128 + k) * 128 + n];
  } else {
    int r = (k - 128) >> 7, d = (k - 128) & 127;
    const float* cp = comps + ((size_t)l * R_REL + r) * 8;
    const float* bp = bases + (((size_t)l * 8) * 128 + d) * 128 + n;
    float s = 0.f;
#pragma unroll
    for (int b = 0; b < 8; ++b) s += cp[b] * bp[(size_t)b * 128 * 128];
    v = s;
  }
  wcat3[t] = f2bf(v);
}

// ---------------------------------------------------------------- histogram (dst,rel)
__global__ __launch_bounds__(256) void hist_kernel(
    const int* __restrict__ ei, const int* __restrict__ et,
    int* __restrict__ cntRel)
{
  int e = blockIdx.x * 256 + threadIdx.x;
  if (e >= E_EDGES) return;
  atomicAdd(&cntRel[ei[E_EDGES + e] * R_REL + et[e]], 1);
}

// ---------------------------------------------------------------- scan over NR
__global__ __launch_bounds__(256) void scanA_kernel(
    const int* __restrict__ cnt, int* __restrict__ tmpOff,
    int* __restrict__ blockSums)
{
  __shared__ int s[256];
  int i = blockIdx.x * 256 + threadIdx.x;
  int v = (i < NR) ? cnt[i] : 0;
  s[threadIdx.x] = v;
  __syncthreads();
#pragma unroll
  for (int d = 1; d < 256; d <<= 1) {
    int t = (threadIdx.x >= d) ? s[threadIdx.x - d] : 0;
    __syncthreads();
    s[threadIdx.x] += t;
    __syncthreads();
  }
  if (i < NR) tmpOff[i] = s[threadIdx.x] - v;   // exclusive within block
  if (threadIdx.x == 255) blockSums[blockIdx.x] = s[255];
}

// single block, serial chunks with carry (SCANR_BLOCKS = 1368)
__global__ __launch_bounds__(256) void scanB_kernel(int* __restrict__ bs)
{
  __shared__ int s[256];
  __shared__ int carry;
  if (threadIdx.x == 0) carry = 0;
  __syncthreads();
  for (int base = 0; base < SCANR_BLOCKS; base += 256) {
    int cOld = carry;
    int i = base + threadIdx.x;
    int v = (i < SCANR_BLOCKS) ? bs[i] : 0;
    s[threadIdx.x] = v;
    __syncthreads();
#pragma unroll
    for (int d = 1; d < 256; d <<= 1) {
      int t = (threadIdx.x >= d) ? s[threadIdx.x - d] : 0;
      __syncthreads();
      s[threadIdx.x] += t;
      __syncthreads();
    }
    if (i < SCANR_BLOCKS) bs[i] = s[threadIdx.x] - v + cOld;  // exclusive
    __syncthreads();
    if (threadIdx.x == 0) carry = cOld + s[255];
    __syncthreads();
  }
}

__global__ __launch_bounds__(256) void scanC_kernel(
    const int* __restrict__ tmpOff, const int* __restrict__ blockSums,
    int* __restrict__ drs)
{
  int i = blockIdx.x * 256 + threadIdx.x;
  if (i < NR) drs[i] = tmpOff[i] + blockSums[blockIdx.x];
  if (i == 0) drs[NR] = E_EDGES;
}

// ---------------------------------------------------------------- placement
__global__ __launch_bounds__(256) void place_kernel(
    const int* __restrict__ ei, const int* __restrict__ et,
    const int* __restrict__ drs, int* __restrict__ cursor,
    unsigned short* __restrict__ esrc)
{
  int e = blockIdx.x * 256 + threadIdx.x;
  if (e >= E_EDGES) return;
  int seg = ei[E_EDGES + e] * R_REL + et[e];
  int pos = drs[seg] + atomicAdd(&cursor[seg], 1);
  esrc[pos] = (unsigned short)ei[e];   // src < 50000 < 65536
}

// ---------------------------------------------------------------- lin1 MFMA GEMM
// M=64 tile (grid 782), K=256 in 2 phases; x read fp32 + cast DURING staging.
// Output: b0 = bf16(t0*(x@w1+b1)) ONLY (no fp32 hidden).
__global__ __launch_bounds__(256) void gemm_lin1(
    const float* __restrict__ x,              // [N,256] fp32
    const unsigned short* __restrict__ BT,    // w1T [128,256] bf16
    const float* __restrict__ bias,
    const float* __restrict__ temp,
    unsigned short* __restrict__ b0out)       // [N,128] bf16
{
  __shared__ unsigned short Atile[64][136];    // 17.4 KB
  __shared__ unsigned short Btile[128][136];   // 34.8 KB
  const int tid  = threadIdx.x;
  const int row0 = blockIdx.x * 64;
  const int lane = tid & 63;
  const int wid  = tid >> 6;
  const int wrow = (wid & 1) * 32;
  const int wcol = (wid >> 1) * 64;
  const int l15  = lane & 15;
  const int quad = lane >> 4;

  floatx4 acc[2][4] = {};

  for (int k0 = 0; k0 < IN_C; k0 += 128) {
#pragma unroll
    for (int it = 0; it < 4; ++it) {
      int chunk = it * 256 + tid;
      int r = chunk >> 4, cc = (chunk & 15) << 3;
      int grow = row0 + r;
      uint4 va = make_uint4(0u, 0u, 0u, 0u);
      if (grow < N_NODES) {
        const float* xp = x + (size_t)grow * IN_C + k0 + cc;
        float4 f0 = *(const float4*)xp;
        float4 f1 = *(const float4*)(xp + 4);
        va.x = (unsigned)f2bf(f0.x) | ((unsigned)f2bf(f0.y) << 16);
        va.y = (unsigned)f2bf(f0.z) | ((unsigned)f2bf(f0.w) << 16);
        va.z = (unsigned)f2bf(f1.x) | ((unsigned)f2bf(f1.y) << 16);
        va.w = (unsigned)f2bf(f1.z) | ((unsigned)f2bf(f1.w) << 16);
      }
      *(uint4*)(&Atile[r][cc]) = va;
    }
#pragma unroll
    for (int it = 0; it < 8; ++it) {
      int chunk = it * 256 + tid;
      int n = chunk >> 4, cc = (chunk & 15) << 3;
      *(uint4*)(&Btile[n][cc]) =
          *(const uint4*)(BT + (size_t)n * IN_C + k0 + cc);
    }
    __syncthreads();
#pragma unroll
    for (int ks = 0; ks < 4; ++ks) {
      int kc = ks * 32 + quad * 8;
      short8 af[2], bfr[4];
#pragma unroll
      for (int i = 0; i < 2; ++i)
        af[i] = *(const short8*)(&Atile[wrow + i * 16 + l15][kc]);
#pragma unroll
      for (int j = 0; j < 4; ++j)
        bfr[j] = *(const short8*)(&Btile[wcol + j * 16 + l15][kc]);
#pragma unroll
      for (int i = 0; i < 2; ++i)
#pragma unroll
        for (int j = 0; j < 4; ++j)
          acc[i][j] = __builtin_amdgcn_mfma_f32_16x16x32_bf16(
              af[i], bfr[j], acc[i][j], 0, 0, 0);
    }
    __syncthreads();
  }

  float t0 = temp[0];
#pragma unroll
  for (int i = 0; i < 2; ++i) {
    int lrow0 = wrow + i * 16 + quad * 4;
#pragma unroll
    for (int j = 0; j < 4; ++j) {
      int gcol = wcol + j * 16 + l15;
      float bb = bias[gcol];
#pragma unroll
      for (int r = 0; r < 4; ++r)
        Atile[lrow0 + r][gcol] = f2bf(t0 * (acc[i][j][r] + bb));
    }
  }
  __syncthreads();
#pragma unroll
  for (int it = 0; it < 4; ++it) {
    int chunk = it * 256 + tid;
    int r = chunk >> 4, cc = (chunk & 15) << 3;
    int grow = row0 + r;
    if (grow < N_NODES)
      *(uint4*)(b0out + (size_t)grow * HID + cc) = *(const uint4*)(&Atile[r][cc]);
  }
}

// ---------------------------------------------------------------- fused RGCN layer
// Block = 16 dsts, 256 threads. Phase 1: agg into LDS (4 dsts/wave, R11 loop).
// Phase 2: GEMM 16x128, K=1024, A from LDS, B coalesced fragment-major global.
__global__ __launch_bounds__(256) void rgcn_block(
    const unsigned short* __restrict__ curA,   // [N,128] bf16 (in, = b_l)
    const unsigned short* __restrict__ esrc,   // sorted by (dst,rel)
    const int* __restrict__ drs,               // [N*R+1] segment starts
    const unsigned short* __restrict__ Bfrag,  // wcat3 layer slice (128x1024)
    const float* __restrict__ bias,
    unsigned short* __restrict__ bout,         // [N,128] bf16 (out)
    int layer)
{
  __shared__ unsigned short Atile[16][AROW];   // 33 KB: [dst][0..127 self | 128+r*128+d]
  const int tid  = threadIdx.x;
  const int lane = tid & 63;
  const int wid  = tid >> 6;
  const int l15  = lane & 15;
  const int quad = lane >> 4;
  const int dst0 = blockIdx.x * 16;
  const unsigned* curW = (const unsigned*)curA;   // 64 uints per node row

  // ---- phase 1: aggregate 4 dsts per wave into LDS (R11's proven loop) ----
  for (int i = 0; i < 4; ++i) {
    int dl  = wid * 4 + i;
    int dst = dst0 + dl;
    if (dst < N_NODES) {
      // self row
      *(unsigned*)(&Atile[dl][lane * 2]) = curW[(size_t)dst * 64 + lane];
      const int segBase = dst * R_REL;
      int bnd = drs[segBase + (lane & 7)];
      const int a0    = __shfl(bnd, 0);
      const int total = __shfl(bnd, 7) - a0;
      int pk = 0;
      if (lane < total) pk = (int)esrc[a0 + lane];   // deg avg 12, <=64 typical
      int p = a0, aPrev = a0;
#pragma unroll
      for (int r = 0; r < R_REL; ++r) {
        int br = __shfl(bnd, r + 1);
        float sx = 0.f, sy = 0.f;
        for (; p < br; ++p) {
          int idx = p - a0;
          int src = (idx < 64) ? __shfl(pk, idx) : (int)esrc[p];
          unsigned v = curW[(size_t)src * 64 + lane];
          sx += bf2f((unsigned short)(v & 0xFFFF));
          sy += bf2f((unsigned short)(v >> 16));
        }
        int c = br - aPrev;
        float sc = (c > 0) ? 1.0f / (float)c : 0.f;
        unsigned pck = (unsigned)f2bf(sx * sc) | ((unsigned)f2bf(sy * sc) << 16);
        *(unsigned*)(&Atile[dl][128 + r * HID + lane * 2]) = pck;
        aPrev = br;
      }
    } else {
#pragma unroll
      for (int c = 0; c < 8; ++c)
        *(unsigned*)(&Atile[dl][c * 128 + lane * 2]) = 0u;
    }
  }
  __syncthreads();

  // ---- phase 2: GEMM. Wave wid owns output cols [wid*32, wid*32+32). ----
  floatx4 acc[2] = {};
  for (int p = 0; p < 8; ++p) {
#pragma unroll
    for (int ks = 0; ks < 4; ++ks) {
      short8 af = *(const short8*)(&Atile[l15][p * 128 + ks * 32 + quad * 8]);
#pragma unroll
      for (int j = 0; j < 2; ++j) {
        const short8 bfr = *(const short8*)(
            Bfrag + ((((size_t)(p * 4 + ks) * 8) + (wid * 2 + j)) * 64 + lane) * 8);
        acc[j] = __builtin_amdgcn_mfma_f32_16x16x32_bf16(af, bfr, acc[j],
                                                         0, 0, 0);
      }
    }
  }

  // ---- epilogue: c = (l<2?relu:id)(acc+bias); bout via LDS transpose ----
  __syncthreads();   // done reading Atile
  const bool isLast = (layer == L_LAYERS - 1);
  const int lrow0 = quad * 4;
#pragma unroll
  for (int j = 0; j < 2; ++j) {
    int gcol = wid * 32 + j * 16 + l15;
    float bb = bias[gcol];
#pragma unroll
    for (int r = 0; r < 4; ++r) {
      float c = acc[j][r] + bb;
      if (!isLast) c = fmaxf(c, 0.f);
      Atile[lrow0 + r][gcol] = f2bf(c);
    }
  }
  __syncthreads();
  {
    int r = tid >> 4, cc = (tid & 15) << 3;
    int grow = dst0 + r;
    if (grow < N_NODES)
      *(uint4*)(bout + (size_t)grow * HID + cc) = *(const uint4*)(&Atile[r][cc]);
  }
}

// ---------------------------------------------------------------- final linear
// h[d] = b0 + temp[1]*b1 + temp[2]*b2 + temp[3]*b3 (bf16 terms), then lin2.
__global__ __launch_bounds__(256) void final_kernel(
    const unsigned short* __restrict__ b0, const unsigned short* __restrict__ b1,
    const unsigned short* __restrict__ b2v, const unsigned short* __restrict__ b3,
    const float* __restrict__ temp,
    const float* __restrict__ w2, const float* __restrict__ b2bias,
    float* __restrict__ out)
{
  int node = blockIdx.x * 4 + (threadIdx.x >> 6);
  int lane = threadIdx.x & 63;
  if (node >= N_NODES) return;
  float t1 = temp[1], t2 = temp[2], t3 = temp[3];
  size_t base = (size_t)node * 64 + lane;      // uint index: dims 2*lane,2*lane+1
  unsigned u0 = ((const unsigned*)b0)[base];
  unsigned u1 = ((const unsigned*)b1)[base];
  unsigned u2 = ((const unsigned*)b2v)[base];
  unsigned u3 = ((const unsigned*)b3)[base];
  float hx = bf2f((unsigned short)(u0 & 0xFFFF)) +
             t1 * bf2f((unsigned short)(u1 & 0xFFFF)) +
             t2 * bf2f((unsigned short)(u2 & 0xFFFF)) +
             t3 * bf2f((unsigned short)(u3 & 0xFFFF));
  float hy = bf2f((unsigned short)(u0 >> 16)) +
             t1 * bf2f((unsigned short)(u1 >> 16)) +
             t2 * bf2f((unsigned short)(u2 >> 16)) +
             t3 * bf2f((unsigned short)(u3 >> 16));
  int d0 = lane * 2, d1 = lane * 2 + 1;
  float a0 = hx * w2[d0 * 2 + 0] + hy * w2[d1 * 2 + 0];
  float a1 = hx * w2[d0 * 2 + 1] + hy * w2[d1 * 2 + 1];
#pragma unroll
  for (int off = 32; off > 0; off >>= 1) {
    a0 += __shfl_down(a0, off);
    a1 += __shfl_down(a1, off);
  }
  if (lane == 0) {
    out[node * 2 + 0] = a0 + b2bias[0];
    out[node * 2 + 1] = a1 + b2bias[1];
  }
}

// ---------------------------------------------------------------- launcher
extern "C" void kernel_launch(void* const* d_in, const int* in_sizes, int n_in,
                              void* d_out, int out_size, void* d_ws, size_t ws_size,
                              hipStream_t stream) {
  const float* x     = (const float*)d_in[0];
  const int*   ei    = (const int*)d_in[1];
  const int*   et    = (const int*)d_in[2];
  const float* temp  = (const float*)d_in[3];
  const float* w1    = (const float*)d_in[4];
  const float* b1    = (const float*)d_in[5];
  const float* w2    = (const float*)d_in[6];
  const float* b2    = (const float*)d_in[7];
  const float* comps = (const float*)d_in[8];
  const float* bases = (const float*)d_in[9];
  const float* roots = (const float*)d_in[10];
  const float* cbias = (const float*)d_in[11];

  char* ws = (char*)d_ws;
  size_t off = 0;
  auto take = [&](size_t bytes) {
    char* p = ws + off;
    off = (off + bytes + 255) & ~(size_t)255;
    return p;
  };
  unsigned short* wcat3 = (unsigned short*)take((size_t)L_LAYERS * 128 * K_CAT * 2); // 0.8 MB
  unsigned short* w1T   = (unsigned short*)take((size_t)HID * IN_C * 2);             // 64 KB
  int*   cntRel  = (int*)take((size_t)NR * 4);                  // 1.4 MB
  int*   tmpOffR = (int*)take((size_t)NR * 4);                  // 1.4 MB
  int*   blockSumsR = (int*)take((size_t)SCANR_BLOCKS * 4);
  int*   drs     = (int*)take((size_t)(NR + 1) * 4);            // 1.4 MB
  int*   cursorR = (int*)take((size_t)NR * 4);                  // 1.4 MB
  unsigned short* esrc = (unsigned short*)take((size_t)E_EDGES * 2); // 1.2 MB
  unsigned short* bl[L_LAYERS + 1];
  for (int i = 0; i <= L_LAYERS; ++i)
    bl[i] = (unsigned short*)take((size_t)N_NODES * HID * 2);   // 4 x 12.8 MB

  hipMemsetAsync(cntRel, 0, (size_t)NR * 4, stream);
  hipMemsetAsync(cursorR, 0, (size_t)NR * 4, stream);

  hipLaunchKernelGGL(build_wcat3, dim3((L_LAYERS * 128 * K_CAT + 255) / 256),
                     dim3(256), 0, stream, comps, bases, roots, wcat3);
  hipLaunchKernelGGL(cast_w1_kernel, dim3((HID * IN_C + 255) / 256), dim3(256),
                     0, stream, w1, w1T);
  hipLaunchKernelGGL(hist_kernel, dim3((E_EDGES + 255) / 256), dim3(256), 0,
                     stream, ei, et, cntRel);
  hipLaunchKernelGGL(scanA_kernel, dim3(SCANR_BLOCKS), dim3(256), 0, stream,
                     cntRel, tmpOffR, blockSumsR);
  hipLaunchKernelGGL(scanB_kernel, dim3(1), dim3(256), 0, stream, blockSumsR);
  hipLaunchKernelGGL(scanC_kernel, dim3(SCANR_BLOCKS), dim3(256), 0, stream,
                     tmpOffR, blockSumsR, drs);
  hipLaunchKernelGGL(place_kernel, dim3((E_EDGES + 255) / 256), dim3(256), 0,
                     stream, ei, et, drs, cursorR, esrc);

  const int rowBlocks64 = (N_NODES + 63) / 64;     // 782
  hipLaunchKernelGGL(gemm_lin1, dim3(rowBlocks64), dim3(256), 0, stream,
                     x, w1T, b1, temp, bl[0]);

  const int fusedBlocks = (N_NODES + 15) / 16;     // 3125
  for (int l = 0; l < L_LAYERS; ++l) {
    hipLaunchKernelGGL(rgcn_block, dim3(fusedBlocks), dim3(256), 0, stream,
                       bl[l], esrc, drs, wcat3 + (size_t)l * 128 * K_CAT,
                       cbias + (size_t)l * HID, bl[l + 1], l);
  }

  hipLaunchKernelGGL(final_kernel, dim3((N_NODES + 3) / 4), dim3(256), 0, stream,
                     bl[0], bl[1], bl[2], bl[3], temp, w2, b2, (float*)d_out);
}